// Round 11
// baseline (5804.226 us; speedup 1.0000x reference)
//
#include <hip/hip_runtime.h>

#define DIM 64
#define PROWS 2048          // rows per scatter partition (localRow fits 11 bits)
#define MAXPART 256         // supports nNodes <= 524288 (2^19 packing limit)
#define CHUNK 8192          // edges per block in pass A
#define SUBROWS 256         // rows per SpMM LDS tile (64 KB)
#define WSHIFT 14           // 16384-row col window = 4 MB source (fits XCD L2)

typedef float f32x4 __attribute__((ext_vector_type(4)));

__device__ __forceinline__ float i2f(int x) { union { int i; float f; } u; u.i = x; return u.f; }

// ---------------- partition-level histogram (LDS-aggregated) ----------------
__global__ __launch_bounds__(256) void k_phist(const int* __restrict__ rows,
                                               int* __restrict__ partCnt,
                                               int nE, int nPart) {
    __shared__ int h[MAXPART];
    for (int t = threadIdx.x; t < nPart; t += 256) h[t] = 0;
    __syncthreads();
    for (long i = (long)blockIdx.x * blockDim.x + threadIdx.x; i < nE;
         i += (long)gridDim.x * blockDim.x)
        atomicAdd(&h[rows[i] >> 11], 1);
    __syncthreads();
    for (int t = threadIdx.x; t < nPart; t += 256) {
        int v = h[t];
        if (v) atomicAdd(&partCnt[t], v);
    }
}

// ---------------- single-block scan over partitions ----------------
__global__ __launch_bounds__(256) void k_pscan(const int* __restrict__ partCnt,
                                               int* __restrict__ partStart,
                                               int* __restrict__ partCurPad,
                                               int nPart, int nE) {
    __shared__ int s[256];
    const int t = threadIdx.x;
    int v = (t < nPart) ? partCnt[t] : 0;
    s[t] = v; __syncthreads();
    for (int off = 1; off < 256; off <<= 1) {
        int tmp = (t >= off) ? s[t - off] : 0;
        __syncthreads();
        s[t] += tmp;
        __syncthreads();
    }
    if (t < nPart) {
        int excl = s[t] - v;
        partStart[t] = excl;
        partCurPad[t * 16] = excl;
    }
    if (t == 0) partStart[nPart] = nE;
}

// ---------------- pass A: COO -> partition-ordered pairs ----------------
__global__ __launch_bounds__(256) void k_scatterP(const int* __restrict__ rows,
                                                  const int* __restrict__ cols,
                                                  const float* __restrict__ vals,
                                                  int* __restrict__ partCurPad,
                                                  int2* __restrict__ pairsA,
                                                  int nE, int nPart) {
    __shared__ int hist[MAXPART];
    __shared__ int runBase[MAXPART];
    const int chunkBase = blockIdx.x * CHUNK;
    int rcache[CHUNK / 256];

    for (int t = threadIdx.x; t < nPart; t += 256) hist[t] = 0;
    __syncthreads();
    #pragma unroll
    for (int j = 0; j < CHUNK / 256; ++j) {
        int i = chunkBase + j * 256 + threadIdx.x;
        int r = (i < nE) ? rows[i] : -1;
        rcache[j] = r;
        if (r >= 0) atomicAdd(&hist[r >> 11], 1);
    }
    __syncthreads();
    for (int t = threadIdx.x; t < nPart; t += 256) {
        int h = hist[t];
        runBase[t] = h ? atomicAdd(&partCurPad[t * 16], h) : 0;
    }
    __syncthreads();
    for (int t = threadIdx.x; t < nPart; t += 256) hist[t] = 0;   // reuse as rank
    __syncthreads();
    #pragma unroll
    for (int j = 0; j < CHUNK / 256; ++j) {
        int i = chunkBase + j * 256 + threadIdx.x;
        int r = rcache[j];
        if (r >= 0) {
            int p = r >> 11;
            int rank = atomicAdd(&hist[p], 1);
            pairsA[runBase[p] + rank] =
                make_int2(((r & (PROWS - 1)) << 19) | cols[i], __float_as_int(vals[i]));
        }
    }
}

// ---------------- pass B: partition-ordered -> (sub-tile, window)-ordered ----
__global__ __launch_bounds__(1024) void k_reorder2(const int* __restrict__ partStart,
                                                   const int2* __restrict__ pairsA,
                                                   int2* __restrict__ pairsB,
                                                   int* __restrict__ subStart,
                                                   int nE, int nPart, int nWin) {
    __shared__ int cnt[256];
    __shared__ int exc[256];
    __shared__ int cur[256];
    const int p = blockIdx.x;
    const int segStart = partStart[p], segEnd = partStart[p + 1];
    const int t = threadIdx.x;
    const int nBuck = 8 * nWin;
    if (t < 256) cnt[t] = 0;
    __syncthreads();
    for (int i = segStart + t; i < segEnd; i += 1024) {
        int2 e = pairsA[i];
        atomicAdd(&cnt[(e.x >> 19 >> 8) * nWin + ((e.x & 0x7FFFF) >> WSHIFT)], 1);
    }
    __syncthreads();
    if (t < 256) exc[t] = cnt[t];
    __syncthreads();
    for (int off = 1; off < 256; off <<= 1) {
        int v = (t < 256 && t >= off) ? exc[t - off] : 0;
        __syncthreads();
        if (t < 256) exc[t] += v;
        __syncthreads();
    }
    if (t < 256) {
        int ex = exc[t] - cnt[t];                 // exclusive
        cur[t] = segStart + ex;
        if (t < nBuck && (t % nWin) == 0)
            subStart[p * 8 + t / nWin] = segStart + ex;
    }
    if (p == nPart - 1 && t == 0) subStart[nPart * 8] = nE;
    __syncthreads();
    for (int i = segStart + t; i < segEnd; i += 1024) {
        int2 e = pairsA[i];
        int lr = e.x >> 19;
        int c  = e.x & 0x7FFFF;
        int b  = (lr >> 8) * nWin + (c >> WSHIFT);
        int pos = atomicAdd(&cur[b], 1);
        pairsB[pos] = make_int2(((lr & (SUBROWS - 1)) << 19) | c, e.y);
    }
}

// ---------------- windowed SpMM hop 1: LDS tile + ds_add_f32 ----------------
__global__ __launch_bounds__(1024) void k_spmmw1(const int* __restrict__ subStart,
                                                 const int2* __restrict__ pairs,
                                                 const float* __restrict__ uE,
                                                 const float* __restrict__ iE,
                                                 float* __restrict__ cur1,
                                                 int nNodes, int nUsers) {
    __shared__ float tile[SUBROWS * DIM];     // 64 KB
    const int lane = threadIdx.x & 63;
    const int wid  = threadIdx.x >> 6;        // 0..15
    const int sub  = blockIdx.x;
    const int r0   = sub * SUBROWS;
    float4* t4 = (float4*)tile;
    for (int i = threadIdx.x; i < SUBROWS * DIM / 4; i += 1024) t4[i] = make_float4(0, 0, 0, 0);
    __syncthreads();
    const int segStart = subStart[sub], segEnd = subStart[sub + 1];
    const int span = segEnd - segStart;
    const int per  = (span + 15) >> 4;
    int eS = segStart + wid * per;
    int eE = eS + per; if (eE > segEnd) eE = segEnd;
    int e = eS;
    for (; e + 7 < eE; e += 8) {
        int eu = __builtin_amdgcn_readfirstlane(e);
        int2 q[8]; float x[8];
        #pragma unroll
        for (int j = 0; j < 8; ++j) q[j] = pairs[eu + j];
        #pragma unroll
        for (int j = 0; j < 8; ++j) {
            int c = q[j].x & 0x7FFFF;
            const float* s = (c < nUsers) ? uE + (size_t)c * DIM
                                          : iE + (size_t)(c - nUsers) * DIM;
            x[j] = s[lane];
        }
        #pragma unroll
        for (int j = 0; j < 8; ++j)
            unsafeAtomicAdd(&tile[(q[j].x >> 19) * DIM + lane], i2f(q[j].y) * x[j]);
    }
    for (; e < eE; ++e) {
        int2 q = pairs[e];
        int c = q.x & 0x7FFFF;
        const float* s = (c < nUsers) ? uE + (size_t)c * DIM
                                      : iE + (size_t)(c - nUsers) * DIM;
        unsafeAtomicAdd(&tile[(q.x >> 19) * DIM + lane], i2f(q.y) * s[lane]);
    }
    __syncthreads();
    int rN = nNodes - r0; if (rN > SUBROWS) rN = SUBROWS;
    if (rN > 0) {
        int n4 = rN * (DIM / 4);
        float4* dst = (float4*)(cur1 + (size_t)r0 * DIM);
        for (int i = threadIdx.x; i < n4; i += 1024) dst[i] = t4[i];
    }
}

// ---------------- windowed SpMM hop 2 + fused epilogue ----------------
__global__ __launch_bounds__(1024) void k_spmmw2(const int* __restrict__ subStart,
                                                 const int2* __restrict__ pairs,
                                                 const float* __restrict__ cur1,
                                                 const float* __restrict__ uE,
                                                 const float* __restrict__ iE,
                                                 float* __restrict__ out,
                                                 int nNodes, int nUsers) {
    __shared__ float tile[SUBROWS * DIM];
    const int lane = threadIdx.x & 63;
    const int wid  = threadIdx.x >> 6;
    const int sub  = blockIdx.x;
    const int r0   = sub * SUBROWS;
    float4* t4 = (float4*)tile;
    for (int i = threadIdx.x; i < SUBROWS * DIM / 4; i += 1024) t4[i] = make_float4(0, 0, 0, 0);
    __syncthreads();
    const int segStart = subStart[sub], segEnd = subStart[sub + 1];
    const int span = segEnd - segStart;
    const int per  = (span + 15) >> 4;
    int eS = segStart + wid * per;
    int eE = eS + per; if (eE > segEnd) eE = segEnd;
    int e = eS;
    for (; e + 7 < eE; e += 8) {
        int eu = __builtin_amdgcn_readfirstlane(e);
        int2 q[8]; float x[8];
        #pragma unroll
        for (int j = 0; j < 8; ++j) q[j] = pairs[eu + j];
        #pragma unroll
        for (int j = 0; j < 8; ++j)
            x[j] = cur1[(size_t)(q[j].x & 0x7FFFF) * DIM + lane];
        #pragma unroll
        for (int j = 0; j < 8; ++j)
            unsafeAtomicAdd(&tile[(q[j].x >> 19) * DIM + lane], i2f(q[j].y) * x[j]);
    }
    for (; e < eE; ++e) {
        int2 q = pairs[e];
        unsafeAtomicAdd(&tile[(q.x >> 19) * DIM + lane],
                        i2f(q.y) * cur1[(size_t)(q.x & 0x7FFFF) * DIM + lane]);
    }
    __syncthreads();
    int rN = nNodes - r0; if (rN > SUBROWS) rN = SUBROWS;
    if (rN > 0) {
        const float inv3 = 1.0f / 3.0f;
        int n4 = rN * (DIM / 4);
        for (int i = threadIdx.x; i < n4; i += 1024) {
            int rr = i >> 4;                 // 16 float4 per row
            int cc = i & 15;
            int r  = r0 + rr;
            float4 tv = t4[i];
            float4 c1 = ((const float4*)cur1)[(size_t)r * 16 + cc];
            float4 em = (r < nUsers) ? ((const float4*)uE)[(size_t)r * 16 + cc]
                                     : ((const float4*)iE)[(size_t)(r - nUsers) * 16 + cc];
            f32x4 o;
            o.x = (em.x + c1.x + tv.x) * inv3;
            o.y = (em.y + c1.y + tv.y) * inv3;
            o.z = (em.z + c1.z + tv.z) * inv3;
            o.w = (em.w + c1.w + tv.w) * inv3;
            __builtin_nontemporal_store(o, (f32x4*)out + (size_t)r * 16 + cc);
        }
    }
}

// ---------------- fallback (round-1 atomic path) ----------------
__global__ __launch_bounds__(256) void spmm_scatter(
    const int* __restrict__ rows, const int* __restrict__ cols,
    const float* __restrict__ vals, const float* __restrict__ srcU,
    const float* __restrict__ srcI, float* __restrict__ dst,
    float scale, int nEdges, int nUsers)
{
    const int lane = threadIdx.x & 63;
    const int wavesPerBlock = blockDim.x >> 6;
    long wave = (long)blockIdx.x * wavesPerBlock + (threadIdx.x >> 6);
    const long nWaves = (long)gridDim.x * wavesPerBlock;
    for (long e = wave; e < nEdges; e += nWaves) {
        const int r = rows[e];
        const int c = cols[e];
        const float v = vals[e] * scale;
        const float* src;
        if (srcI != nullptr) {
            src = (c < nUsers) ? (srcU + (size_t)c * DIM)
                               : (srcI + (size_t)(c - nUsers) * DIM);
        } else {
            src = srcU + (size_t)c * DIM;
        }
        atomicAdd(dst + (size_t)r * DIM + lane, v * src[lane]);
    }
}

__global__ __launch_bounds__(256) void finalize_base(
    const float* __restrict__ userE, const float* __restrict__ itemE,
    const float* __restrict__ cur1, float* __restrict__ out, int nNodes, int nUsers)
{
    const long total4 = (long)nNodes * DIM / 4;
    const long user4  = (long)nUsers * DIM / 4;
    const float inv3 = 1.0f / 3.0f;
    for (long i = (long)blockIdx.x * blockDim.x + threadIdx.x; i < total4;
         i += (long)gridDim.x * blockDim.x) {
        float4 e = (i < user4) ? ((const float4*)userE)[i]
                               : ((const float4*)itemE)[i - user4];
        float4 c = ((const float4*)cur1)[i];
        float4 o;
        o.x = (e.x + c.x) * inv3; o.y = (e.y + c.y) * inv3;
        o.z = (e.z + c.z) * inv3; o.w = (e.w + c.w) * inv3;
        ((float4*)out)[i] = o;
    }
}

// ----------------------------------------------------------------

static inline size_t align256(size_t x) { return (x + 255) & ~(size_t)255; }

extern "C" void kernel_launch(void* const* d_in, const int* in_sizes, int n_in,
                              void* d_out, int out_size, void* d_ws, size_t ws_size,
                              hipStream_t stream)
{
    const int*   rows  = (const int*)d_in[0];
    const int*   cols  = (const int*)d_in[1];
    const float* vals  = (const float*)d_in[2];
    const float* userE = (const float*)d_in[3];
    const float* itemE = (const float*)d_in[4];
    float* out = (float*)d_out;

    const int nE     = in_sizes[0];
    const int nUsers = in_sizes[3] / DIM;
    const int nItems = in_sizes[4] / DIM;
    const int nNodes = nUsers + nItems;
    const int nPart  = (nNodes + PROWS - 1) / PROWS;
    const int nWin   = (nNodes + (1 << WSHIFT) - 1) >> WSHIFT;
    const int nSub   = nPart * 8;

    // ws layout:
    //   [region0: max(cur1, pairsA)]  pairsA first; spmmw1 overwrites with cur1
    //   [pairsB][subStart][partStart][partCurPad][partCnt]
    const size_t cur1B    = (size_t)nNodes * DIM * sizeof(float);
    const size_t pairsAB  = (size_t)nE * sizeof(int2);
    const size_t reg0B    = cur1B > pairsAB ? cur1B : pairsAB;
    const size_t pbOff    = align256(reg0B);
    const size_t pbB      = (size_t)nE * sizeof(int2);
    const size_t ssOff    = align256(pbOff + pbB);
    const size_t ssB      = ((size_t)nSub + 1) * sizeof(int);
    const size_t psOff    = align256(ssOff + ssB);
    const size_t psB      = ((size_t)MAXPART + 1) * sizeof(int);
    const size_t pcOff    = align256(psOff + psB);
    const size_t pcB      = (size_t)MAXPART * 16 * sizeof(int);
    const size_t cntOff   = align256(pcOff + pcB);
    const size_t cntB     = (size_t)MAXPART * sizeof(int);
    const size_t required = cntOff + cntB;

    char* ws = (char*)d_ws;
    float* cur1   = (float*)ws;
    int2*  pairsA = (int2*)ws;                 // same region as cur1
    int2*  pairsB = (int2*)(ws + pbOff);

    if (ws_size >= required && nNodes < (1 << 19) && nPart <= MAXPART && nWin <= 32) {
        int* subStart   = (int*)(ws + ssOff);
        int* partStart  = (int*)(ws + psOff);
        int* partCurPad = (int*)(ws + pcOff);
        int* partCnt    = (int*)(ws + cntOff);

        const int nChunks = (nE + CHUNK - 1) / CHUNK;

        hipMemsetAsync(partCnt, 0, (size_t)nPart * sizeof(int), stream);
        k_phist<<<dim3(512), dim3(256), 0, stream>>>(rows, partCnt, nE, nPart);
        k_pscan<<<dim3(1), dim3(256), 0, stream>>>(partCnt, partStart, partCurPad,
                                                   nPart, nE);
        k_scatterP<<<dim3(nChunks), dim3(256), 0, stream>>>(rows, cols, vals,
                                                            partCurPad, pairsA, nE, nPart);
        k_reorder2<<<dim3(nPart), dim3(1024), 0, stream>>>(partStart, pairsA, pairsB,
                                                           subStart, nE, nPart, nWin);
        // spmmw1 overwrites pairsA region with cur1 (pairsA dead after reorder2)
        k_spmmw1<<<dim3(nSub), dim3(1024), 0, stream>>>(subStart, pairsB, userE, itemE,
                                                        cur1, nNodes, nUsers);
        k_spmmw2<<<dim3(nSub), dim3(1024), 0, stream>>>(subStart, pairsB, cur1, userE,
                                                        itemE, out, nNodes, nUsers);
    } else {
        // fallback: atomic scatter path (round-1)
        hipMemsetAsync(cur1, 0, cur1B, stream);
        dim3 blk(256);
        spmm_scatter<<<dim3(4096), blk, 0, stream>>>(rows, cols, vals, userE, itemE,
                                                     cur1, 1.0f, nE, nUsers);
        finalize_base<<<dim3(2048), blk, 0, stream>>>(userE, itemE, cur1, out,
                                                      nNodes, nUsers);
        spmm_scatter<<<dim3(4096), blk, 0, stream>>>(rows, cols, vals, cur1, nullptr,
                                                     out, 1.0f / 3.0f, nE, nUsers);
    }
}

// Round 12
// 858.678 us; speedup vs baseline: 6.7595x; 6.7595x over previous
//
#include <hip/hip_runtime.h>

#define DIM 64
#define PROWS 2048          // rows per partition (localRow fits 11 bits)
#define MAXPART 256         // supports nNodes <= 524288 (= 2^19 packing limit)
#define CHUNK 8192          // edges per block in pass A

__device__ __forceinline__ float i2f(int x) { union { int i; float f; } u; u.i = x; return u.f; }

// ---------------- partition-level histogram (LDS-aggregated) ----------------
__global__ __launch_bounds__(256) void k_phist(const int* __restrict__ rows,
                                               int* __restrict__ partCnt,
                                               int nE, int nPart) {
    __shared__ int h[MAXPART];
    for (int t = threadIdx.x; t < nPart; t += 256) h[t] = 0;
    __syncthreads();
    for (long i = (long)blockIdx.x * blockDim.x + threadIdx.x; i < nE;
         i += (long)gridDim.x * blockDim.x)
        atomicAdd(&h[rows[i] >> 11], 1);
    __syncthreads();
    for (int t = threadIdx.x; t < nPart; t += 256) {
        int v = h[t];
        if (v) atomicAdd(&partCnt[t], v);
    }
}

// ---------------- single-block scan over partitions ----------------
__global__ __launch_bounds__(256) void k_pscan(const int* __restrict__ partCnt,
                                               int* __restrict__ partStart,
                                               int* __restrict__ partCurPad,
                                               int nPart, int nE) {
    __shared__ int s[256];
    const int t = threadIdx.x;
    int v = (t < nPart) ? partCnt[t] : 0;
    s[t] = v; __syncthreads();
    for (int off = 1; off < 256; off <<= 1) {
        int tmp = (t >= off) ? s[t - off] : 0;
        __syncthreads();
        s[t] += tmp;
        __syncthreads();
    }
    if (t < nPart) {
        int excl = s[t] - v;
        partStart[t] = excl;
        partCurPad[t * 16] = excl;
    }
    if (t == 0) partStart[nPart] = nE;
}

// ---------------- pass A: COO -> partition-ordered pairs ----------------
__global__ __launch_bounds__(256) void k_scatterP(const int* __restrict__ rows,
                                                  const int* __restrict__ cols,
                                                  const float* __restrict__ vals,
                                                  int* __restrict__ partCurPad,
                                                  int2* __restrict__ pairsA,
                                                  int nE, int nPart) {
    __shared__ int hist[MAXPART];
    __shared__ int runBase[MAXPART];
    const int chunkBase = blockIdx.x * CHUNK;
    int rcache[CHUNK / 256];

    for (int t = threadIdx.x; t < nPart; t += 256) hist[t] = 0;
    __syncthreads();
    #pragma unroll
    for (int j = 0; j < CHUNK / 256; ++j) {
        int i = chunkBase + j * 256 + threadIdx.x;
        int r = (i < nE) ? rows[i] : -1;
        rcache[j] = r;
        if (r >= 0) atomicAdd(&hist[r >> 11], 1);
    }
    __syncthreads();
    for (int t = threadIdx.x; t < nPart; t += 256) {
        int h = hist[t];
        runBase[t] = h ? atomicAdd(&partCurPad[t * 16], h) : 0;
    }
    __syncthreads();
    for (int t = threadIdx.x; t < nPart; t += 256) hist[t] = 0;   // reuse as rank
    __syncthreads();
    #pragma unroll
    for (int j = 0; j < CHUNK / 256; ++j) {
        int i = chunkBase + j * 256 + threadIdx.x;
        int r = rcache[j];
        if (r >= 0) {
            int p = r >> 11;
            int rank = atomicAdd(&hist[p], 1);
            pairsA[runBase[p] + rank] =
                make_int2(((r & (PROWS - 1)) << 19) | cols[i], __float_as_int(vals[i]));
        }
    }
}

// ---------------- fused: row-hist + scan + reorder -> exact CSR + rowStart ----
__global__ __launch_bounds__(1024) void k_buildCSR(const int* __restrict__ partStart,
                                                   const int2* __restrict__ pairsA,
                                                   int2* __restrict__ pairsCSR,
                                                   int* __restrict__ rowStart,
                                                   int nNodes, int nE, int nPart) {
    __shared__ int hist[PROWS];
    __shared__ int cur[PROWS];
    __shared__ int s[1024];
    const int p  = blockIdx.x;
    const int r0 = p * PROWS;
    const int segStart = partStart[p], segEnd = partStart[p + 1];
    const int t = threadIdx.x;

    hist[t] = 0; hist[t + 1024] = 0;
    __syncthreads();
    for (int i = segStart + t; i < segEnd; i += 1024)
        atomicAdd(&hist[pairsA[i].x >> 19], 1);
    __syncthreads();

    int a0 = hist[2 * t], a1 = hist[2 * t + 1];
    s[t] = a0 + a1;
    __syncthreads();
    for (int off = 1; off < 1024; off <<= 1) {
        int tmp = (t >= off) ? s[t - off] : 0;
        __syncthreads();
        s[t] += tmp;
        __syncthreads();
    }
    int pairExcl = s[t] - (a0 + a1);
    cur[2 * t]     = segStart + pairExcl;
    cur[2 * t + 1] = segStart + pairExcl + a0;
    __syncthreads();

    int rN = nNodes - r0; if (rN > PROWS) rN = PROWS;
    for (int j = t; j < rN; j += 1024) rowStart[r0 + j] = cur[j];
    if (p == nPart - 1 && t == 0) rowStart[nNodes] = nE;
    __syncthreads();

    for (int i = segStart + t; i < segEnd; i += 1024) {
        int2 e = pairsA[i];
        int lr = e.x >> 19;
        int pos = atomicAdd(&cur[lr], 1);
        pairsCSR[pos] = make_int2(e.x & 0x7FFFF, e.y);
    }
}

// ---------------- SpMM: one wave per row, lane = dim, unroll x16 ----------------
__global__ __launch_bounds__(256) void k_spmm1(const int* __restrict__ rowStart,
                                               const int2* __restrict__ pairs,
                                               const float* __restrict__ uE,
                                               const float* __restrict__ iE,
                                               float* __restrict__ cur1,
                                               int nNodes, int nUsers) {
    const int lane = threadIdx.x & 63;
    int r = blockIdx.x * (blockDim.x >> 6) + (threadIdx.x >> 6);
    if (r >= nNodes) return;
    int start = __builtin_amdgcn_readfirstlane(rowStart[r]);
    int end   = __builtin_amdgcn_readfirstlane(rowStart[r + 1]);
    float acc = 0.f;
    int e = start;
    for (; e + 15 < end; e += 16) {
        int2 p[16]; float x[16];
        #pragma unroll
        for (int j = 0; j < 16; ++j) p[j] = pairs[e + j];
        #pragma unroll
        for (int j = 0; j < 16; ++j) {
            const float* s = (p[j].x < nUsers) ? uE + (size_t)p[j].x * DIM
                                               : iE + (size_t)(p[j].x - nUsers) * DIM;
            x[j] = s[lane];
        }
        #pragma unroll
        for (int j = 0; j < 16; ++j) acc = fmaf(i2f(p[j].y), x[j], acc);
    }
    for (; e + 7 < end; e += 8) {
        int2 p[8]; float x[8];
        #pragma unroll
        for (int j = 0; j < 8; ++j) p[j] = pairs[e + j];
        #pragma unroll
        for (int j = 0; j < 8; ++j) {
            const float* s = (p[j].x < nUsers) ? uE + (size_t)p[j].x * DIM
                                               : iE + (size_t)(p[j].x - nUsers) * DIM;
            x[j] = s[lane];
        }
        #pragma unroll
        for (int j = 0; j < 8; ++j) acc = fmaf(i2f(p[j].y), x[j], acc);
    }
    for (; e + 3 < end; e += 4) {
        int2 p[4]; float x[4];
        #pragma unroll
        for (int j = 0; j < 4; ++j) p[j] = pairs[e + j];
        #pragma unroll
        for (int j = 0; j < 4; ++j) {
            const float* s = (p[j].x < nUsers) ? uE + (size_t)p[j].x * DIM
                                               : iE + (size_t)(p[j].x - nUsers) * DIM;
            x[j] = s[lane];
        }
        #pragma unroll
        for (int j = 0; j < 4; ++j) acc = fmaf(i2f(p[j].y), x[j], acc);
    }
    for (; e < end; ++e) {
        int2 p = pairs[e];
        const float* s = (p.x < nUsers) ? uE + (size_t)p.x * DIM
                                        : iE + (size_t)(p.x - nUsers) * DIM;
        acc = fmaf(i2f(p.y), s[lane], acc);
    }
    cur1[(size_t)r * DIM + lane] = acc;
}

__global__ __launch_bounds__(256) void k_spmm2(const int* __restrict__ rowStart,
                                               const int2* __restrict__ pairs,
                                               const float* __restrict__ cur1,
                                               const float* __restrict__ uE,
                                               const float* __restrict__ iE,
                                               float* __restrict__ out,
                                               int nNodes, int nUsers) {
    const int lane = threadIdx.x & 63;
    int r = blockIdx.x * (blockDim.x >> 6) + (threadIdx.x >> 6);
    if (r >= nNodes) return;
    int start = __builtin_amdgcn_readfirstlane(rowStart[r]);
    int end   = __builtin_amdgcn_readfirstlane(rowStart[r + 1]);
    float acc = 0.f;
    int e = start;
    for (; e + 15 < end; e += 16) {
        int2 p[16]; float x[16];
        #pragma unroll
        for (int j = 0; j < 16; ++j) p[j] = pairs[e + j];
        #pragma unroll
        for (int j = 0; j < 16; ++j) x[j] = cur1[(size_t)p[j].x * DIM + lane];
        #pragma unroll
        for (int j = 0; j < 16; ++j) acc = fmaf(i2f(p[j].y), x[j], acc);
    }
    for (; e + 7 < end; e += 8) {
        int2 p[8]; float x[8];
        #pragma unroll
        for (int j = 0; j < 8; ++j) p[j] = pairs[e + j];
        #pragma unroll
        for (int j = 0; j < 8; ++j) x[j] = cur1[(size_t)p[j].x * DIM + lane];
        #pragma unroll
        for (int j = 0; j < 8; ++j) acc = fmaf(i2f(p[j].y), x[j], acc);
    }
    for (; e + 3 < end; e += 4) {
        int2 p[4]; float x[4];
        #pragma unroll
        for (int j = 0; j < 4; ++j) p[j] = pairs[e + j];
        #pragma unroll
        for (int j = 0; j < 4; ++j) x[j] = cur1[(size_t)p[j].x * DIM + lane];
        #pragma unroll
        for (int j = 0; j < 4; ++j) acc = fmaf(i2f(p[j].y), x[j], acc);
    }
    for (; e < end; ++e) {
        int2 p = pairs[e];
        acc = fmaf(i2f(p.y), cur1[(size_t)p.x * DIM + lane], acc);
    }
    float em = (r < nUsers) ? uE[(size_t)r * DIM + lane]
                            : iE[(size_t)(r - nUsers) * DIM + lane];
    float o = (em + cur1[(size_t)r * DIM + lane] + acc) * (1.0f / 3.0f);
    __builtin_nontemporal_store(o, &out[(size_t)r * DIM + lane]);
}

// ---------------- fallback (round-1 atomic path) ----------------
__global__ __launch_bounds__(256) void spmm_scatter(
    const int* __restrict__ rows, const int* __restrict__ cols,
    const float* __restrict__ vals, const float* __restrict__ srcU,
    const float* __restrict__ srcI, float* __restrict__ dst,
    float scale, int nEdges, int nUsers)
{
    const int lane = threadIdx.x & 63;
    const int wavesPerBlock = blockDim.x >> 6;
    long wave = (long)blockIdx.x * wavesPerBlock + (threadIdx.x >> 6);
    const long nWaves = (long)gridDim.x * wavesPerBlock;
    for (long e = wave; e < nEdges; e += nWaves) {
        const int r = rows[e];
        const int c = cols[e];
        const float v = vals[e] * scale;
        const float* src;
        if (srcI != nullptr) {
            src = (c < nUsers) ? (srcU + (size_t)c * DIM)
                               : (srcI + (size_t)(c - nUsers) * DIM);
        } else {
            src = srcU + (size_t)c * DIM;
        }
        atomicAdd(dst + (size_t)r * DIM + lane, v * src[lane]);
    }
}

__global__ __launch_bounds__(256) void finalize_base(
    const float* __restrict__ userE, const float* __restrict__ itemE,
    const float* __restrict__ cur1, float* __restrict__ out, int nNodes, int nUsers)
{
    const long total4 = (long)nNodes * DIM / 4;
    const long user4  = (long)nUsers * DIM / 4;
    const float inv3 = 1.0f / 3.0f;
    for (long i = (long)blockIdx.x * blockDim.x + threadIdx.x; i < total4;
         i += (long)gridDim.x * blockDim.x) {
        float4 e = (i < user4) ? ((const float4*)userE)[i]
                               : ((const float4*)itemE)[i - user4];
        float4 c = ((const float4*)cur1)[i];
        float4 o;
        o.x = (e.x + c.x) * inv3; o.y = (e.y + c.y) * inv3;
        o.z = (e.z + c.z) * inv3; o.w = (e.w + c.w) * inv3;
        ((float4*)out)[i] = o;
    }
}

// ----------------------------------------------------------------

static inline size_t align256(size_t x) { return (x + 255) & ~(size_t)255; }

extern "C" void kernel_launch(void* const* d_in, const int* in_sizes, int n_in,
                              void* d_out, int out_size, void* d_ws, size_t ws_size,
                              hipStream_t stream)
{
    const int*   rows  = (const int*)d_in[0];
    const int*   cols  = (const int*)d_in[1];
    const float* vals  = (const float*)d_in[2];
    const float* userE = (const float*)d_in[3];
    const float* itemE = (const float*)d_in[4];
    float* out = (float*)d_out;

    const int nE     = in_sizes[0];
    const int nUsers = in_sizes[3] / DIM;
    const int nItems = in_sizes[4] / DIM;
    const int nNodes = nUsers + nItems;
    const int nPart  = (nNodes + PROWS - 1) / PROWS;

    // ws layout:
    //   [region0: max(cur1, pairsA)]  pairsA first; spmm1 later overwrites with cur1
    //   [pairsCSR][rowStart][partStart][partCurPad][partCnt]
    const size_t cur1B    = (size_t)nNodes * DIM * sizeof(float);
    const size_t pairsAB  = (size_t)nE * sizeof(int2);
    const size_t reg0B    = cur1B > pairsAB ? cur1B : pairsAB;
    const size_t csrOff   = align256(reg0B);
    const size_t csrB     = (size_t)nE * sizeof(int2);
    const size_t rsOff    = align256(csrOff + csrB);
    const size_t rsB      = ((size_t)nNodes + 1) * sizeof(int);
    const size_t psOff    = align256(rsOff + rsB);
    const size_t psB      = ((size_t)MAXPART + 1) * sizeof(int);
    const size_t pcOff    = align256(psOff + psB);
    const size_t pcB      = (size_t)MAXPART * 16 * sizeof(int);
    const size_t cntOff   = align256(pcOff + pcB);
    const size_t cntB     = (size_t)MAXPART * sizeof(int);
    const size_t required = cntOff + cntB;

    char* ws = (char*)d_ws;
    float* cur1     = (float*)ws;
    int2*  pairsA   = (int2*)ws;                 // same region as cur1
    int2*  pairsCSR = (int2*)(ws + csrOff);

    if (ws_size >= required && nNodes <= MAXPART * PROWS && nNodes < (1 << 19)) {
        int* rowStart   = (int*)(ws + rsOff);
        int* partStart  = (int*)(ws + psOff);
        int* partCurPad = (int*)(ws + pcOff);
        int* partCnt    = (int*)(ws + cntOff);

        const int nChunks = (nE + CHUNK - 1) / CHUNK;

        hipMemsetAsync(partCnt, 0, (size_t)nPart * sizeof(int), stream);
        k_phist<<<dim3(512), dim3(256), 0, stream>>>(rows, partCnt, nE, nPart);
        k_pscan<<<dim3(1), dim3(256), 0, stream>>>(partCnt, partStart, partCurPad,
                                                   nPart, nE);
        k_scatterP<<<dim3(nChunks), dim3(256), 0, stream>>>(rows, cols, vals,
                                                            partCurPad, pairsA, nE, nPart);
        k_buildCSR<<<dim3(nPart), dim3(1024), 0, stream>>>(partStart, pairsA, pairsCSR,
                                                           rowStart, nNodes, nE, nPart);

        const int rowsPerBlock = 4;
        dim3 sgrid((nNodes + rowsPerBlock - 1) / rowsPerBlock), sblk(256);
        // spmm1 overwrites pairsA region with cur1 (pairsA dead after buildCSR)
        k_spmm1<<<sgrid, sblk, 0, stream>>>(rowStart, pairsCSR, userE, itemE, cur1,
                                            nNodes, nUsers);
        k_spmm2<<<sgrid, sblk, 0, stream>>>(rowStart, pairsCSR, cur1, userE, itemE, out,
                                            nNodes, nUsers);
    } else {
        // fallback: atomic scatter path (round-1)
        hipMemsetAsync(cur1, 0, cur1B, stream);
        dim3 blk(256);
        spmm_scatter<<<dim3(4096), blk, 0, stream>>>(rows, cols, vals, userE, itemE,
                                                     cur1, 1.0f, nE, nUsers);
        finalize_base<<<dim3(2048), blk, 0, stream>>>(userE, itemE, cur1, out,
                                                      nNodes, nUsers);
        spmm_scatter<<<dim3(4096), blk, 0, stream>>>(rows, cols, vals, cur1, nullptr,
                                                     out, 1.0f / 3.0f, nE, nUsers);
    }
}

// Round 13
// 644.735 us; speedup vs baseline: 9.0025x; 1.3318x over previous
//
#include <hip/hip_runtime.h>

#define DIM 64
#define PROWS 2048          // rows per partition (localRow fits 11 bits)
#define MAXPART 256         // supports nNodes <= 524288 (= 2^19 packing limit)
#define CHUNK 8192          // edges per block in pass A

__device__ __forceinline__ float i2f(int x) { union { int i; float f; } u; u.i = x; return u.f; }
__device__ __forceinline__ float b2f(ushort u) { return __uint_as_float(((unsigned)u) << 16); }
__device__ __forceinline__ ushort f2b(float x) {           // round-to-nearest-even
    unsigned b = __float_as_uint(x);
    b += 0x7FFFu + ((b >> 16) & 1u);
    return (ushort)(b >> 16);
}
__device__ __forceinline__ unsigned pk(float x, float y) {
    return (unsigned)f2b(x) | ((unsigned)f2b(y) << 16);
}

// ---------------- partition-level histogram (LDS-aggregated) ----------------
__global__ __launch_bounds__(256) void k_phist(const int* __restrict__ rows,
                                               int* __restrict__ partCnt,
                                               int nE, int nPart) {
    __shared__ int h[MAXPART];
    for (int t = threadIdx.x; t < nPart; t += 256) h[t] = 0;
    __syncthreads();
    for (long i = (long)blockIdx.x * blockDim.x + threadIdx.x; i < nE;
         i += (long)gridDim.x * blockDim.x)
        atomicAdd(&h[rows[i] >> 11], 1);
    __syncthreads();
    for (int t = threadIdx.x; t < nPart; t += 256) {
        int v = h[t];
        if (v) atomicAdd(&partCnt[t], v);
    }
}

// ---------------- single-block scan over partitions ----------------
__global__ __launch_bounds__(256) void k_pscan(const int* __restrict__ partCnt,
                                               int* __restrict__ partStart,
                                               int* __restrict__ partCurPad,
                                               int nPart, int nE) {
    __shared__ int s[256];
    const int t = threadIdx.x;
    int v = (t < nPart) ? partCnt[t] : 0;
    s[t] = v; __syncthreads();
    for (int off = 1; off < 256; off <<= 1) {
        int tmp = (t >= off) ? s[t - off] : 0;
        __syncthreads();
        s[t] += tmp;
        __syncthreads();
    }
    if (t < nPart) {
        int excl = s[t] - v;
        partStart[t] = excl;
        partCurPad[t * 16] = excl;
    }
    if (t == 0) partStart[nPart] = nE;
}

// ---------------- pass A: COO -> partition-ordered pairs ----------------
__global__ __launch_bounds__(256) void k_scatterP(const int* __restrict__ rows,
                                                  const int* __restrict__ cols,
                                                  const float* __restrict__ vals,
                                                  int* __restrict__ partCurPad,
                                                  int2* __restrict__ pairsA,
                                                  int nE, int nPart) {
    __shared__ int hist[MAXPART];
    __shared__ int runBase[MAXPART];
    const int chunkBase = blockIdx.x * CHUNK;
    int rcache[CHUNK / 256];

    for (int t = threadIdx.x; t < nPart; t += 256) hist[t] = 0;
    __syncthreads();
    #pragma unroll
    for (int j = 0; j < CHUNK / 256; ++j) {
        int i = chunkBase + j * 256 + threadIdx.x;
        int r = (i < nE) ? rows[i] : -1;
        rcache[j] = r;
        if (r >= 0) atomicAdd(&hist[r >> 11], 1);
    }
    __syncthreads();
    for (int t = threadIdx.x; t < nPart; t += 256) {
        int h = hist[t];
        runBase[t] = h ? atomicAdd(&partCurPad[t * 16], h) : 0;
    }
    __syncthreads();
    for (int t = threadIdx.x; t < nPart; t += 256) hist[t] = 0;   // reuse as rank
    __syncthreads();
    #pragma unroll
    for (int j = 0; j < CHUNK / 256; ++j) {
        int i = chunkBase + j * 256 + threadIdx.x;
        int r = rcache[j];
        if (r >= 0) {
            int p = r >> 11;
            int rank = atomicAdd(&hist[p], 1);
            pairsA[runBase[p] + rank] =
                make_int2(((r & (PROWS - 1)) << 19) | cols[i], __float_as_int(vals[i]));
        }
    }
}

// ---------------- fused: row-hist + scan + reorder -> exact CSR + rowStart ----
__global__ __launch_bounds__(1024) void k_buildCSR(const int* __restrict__ partStart,
                                                   const int2* __restrict__ pairsA,
                                                   int2* __restrict__ pairsCSR,
                                                   int* __restrict__ rowStart,
                                                   int nNodes, int nE, int nPart) {
    __shared__ int hist[PROWS];
    __shared__ int cur[PROWS];
    __shared__ int s[1024];
    const int p  = blockIdx.x;
    const int r0 = p * PROWS;
    const int segStart = partStart[p], segEnd = partStart[p + 1];
    const int t = threadIdx.x;

    hist[t] = 0; hist[t + 1024] = 0;
    __syncthreads();
    for (int i = segStart + t; i < segEnd; i += 1024)
        atomicAdd(&hist[pairsA[i].x >> 19], 1);
    __syncthreads();

    int a0 = hist[2 * t], a1 = hist[2 * t + 1];
    s[t] = a0 + a1;
    __syncthreads();
    for (int off = 1; off < 1024; off <<= 1) {
        int tmp = (t >= off) ? s[t - off] : 0;
        __syncthreads();
        s[t] += tmp;
        __syncthreads();
    }
    int pairExcl = s[t] - (a0 + a1);
    cur[2 * t]     = segStart + pairExcl;
    cur[2 * t + 1] = segStart + pairExcl + a0;
    __syncthreads();

    int rN = nNodes - r0; if (rN > PROWS) rN = PROWS;
    for (int j = t; j < rN; j += 1024) rowStart[r0 + j] = cur[j];
    if (p == nPart - 1 && t == 0) rowStart[nNodes] = nE;
    __syncthreads();

    for (int i = segStart + t; i < segEnd; i += 1024) {
        int2 e = pairsA[i];
        int lr = e.x >> 19;
        int pos = atomicAdd(&cur[lr], 1);
        pairsCSR[pos] = make_int2(e.x & 0x7FFFF, e.y);
    }
}

// ---------------- convert concat(uE,iE) f32 -> bf16 (8 elems/thread) ----------
__global__ __launch_bounds__(256) void k_toBf16(const float* __restrict__ uE,
                                                const float* __restrict__ iE,
                                                ushort* __restrict__ embB,
                                                int nNodes, int nUsers) {
    const long total8 = (long)nNodes * DIM / 8;
    const long user8  = (long)nUsers * DIM / 8;
    for (long i = (long)blockIdx.x * blockDim.x + threadIdx.x; i < total8;
         i += (long)gridDim.x * blockDim.x) {
        const float4* p = (i < user8) ? (const float4*)uE + 2 * i
                                      : (const float4*)iE + 2 * (i - user8);
        float4 a = p[0], b = p[1];
        uint4 o;
        o.x = pk(a.x, a.y); o.y = pk(a.z, a.w);
        o.z = pk(b.x, b.y); o.w = pk(b.z, b.w);
        ((uint4*)embB)[i] = o;
    }
}

// ---------------- SpMM hop1 (bf16 gather): wave per row, lane = dim ------------
__global__ __launch_bounds__(256) void k_spmm1(const int* __restrict__ rowStart,
                                               const int2* __restrict__ pairs,
                                               const ushort* __restrict__ embB,
                                               ushort* __restrict__ cur1B,
                                               int nNodes) {
    const int lane = threadIdx.x & 63;
    int r = blockIdx.x * (blockDim.x >> 6) + (threadIdx.x >> 6);
    if (r >= nNodes) return;
    int start = __builtin_amdgcn_readfirstlane(rowStart[r]);
    int end   = __builtin_amdgcn_readfirstlane(rowStart[r + 1]);
    float acc = 0.f;
    int e = start;
    for (; e + 7 < end; e += 8) {
        int2 p[8]; float x[8];
        #pragma unroll
        for (int j = 0; j < 8; ++j) p[j] = pairs[e + j];
        #pragma unroll
        for (int j = 0; j < 8; ++j) x[j] = b2f(embB[(size_t)p[j].x * DIM + lane]);
        #pragma unroll
        for (int j = 0; j < 8; ++j) acc = fmaf(i2f(p[j].y), x[j], acc);
    }
    for (; e + 3 < end; e += 4) {
        int2 p[4]; float x[4];
        #pragma unroll
        for (int j = 0; j < 4; ++j) p[j] = pairs[e + j];
        #pragma unroll
        for (int j = 0; j < 4; ++j) x[j] = b2f(embB[(size_t)p[j].x * DIM + lane]);
        #pragma unroll
        for (int j = 0; j < 4; ++j) acc = fmaf(i2f(p[j].y), x[j], acc);
    }
    for (; e < end; ++e) {
        int2 p = pairs[e];
        acc = fmaf(i2f(p.y), b2f(embB[(size_t)p.x * DIM + lane]), acc);
    }
    cur1B[(size_t)r * DIM + lane] = f2b(acc);
}

// ---------------- SpMM hop2 (bf16 gather) + fused epilogue --------------------
__global__ __launch_bounds__(256) void k_spmm2(const int* __restrict__ rowStart,
                                               const int2* __restrict__ pairs,
                                               const ushort* __restrict__ cur1B,
                                               const float* __restrict__ uE,
                                               const float* __restrict__ iE,
                                               float* __restrict__ out,
                                               int nNodes, int nUsers) {
    const int lane = threadIdx.x & 63;
    int r = blockIdx.x * (blockDim.x >> 6) + (threadIdx.x >> 6);
    if (r >= nNodes) return;
    int start = __builtin_amdgcn_readfirstlane(rowStart[r]);
    int end   = __builtin_amdgcn_readfirstlane(rowStart[r + 1]);
    float acc = 0.f;
    int e = start;
    for (; e + 7 < end; e += 8) {
        int2 p[8]; float x[8];
        #pragma unroll
        for (int j = 0; j < 8; ++j) p[j] = pairs[e + j];
        #pragma unroll
        for (int j = 0; j < 8; ++j) x[j] = b2f(cur1B[(size_t)p[j].x * DIM + lane]);
        #pragma unroll
        for (int j = 0; j < 8; ++j) acc = fmaf(i2f(p[j].y), x[j], acc);
    }
    for (; e + 3 < end; e += 4) {
        int2 p[4]; float x[4];
        #pragma unroll
        for (int j = 0; j < 4; ++j) p[j] = pairs[e + j];
        #pragma unroll
        for (int j = 0; j < 4; ++j) x[j] = b2f(cur1B[(size_t)p[j].x * DIM + lane]);
        #pragma unroll
        for (int j = 0; j < 4; ++j) acc = fmaf(i2f(p[j].y), x[j], acc);
    }
    for (; e < end; ++e) {
        int2 p = pairs[e];
        acc = fmaf(i2f(p.y), b2f(cur1B[(size_t)p.x * DIM + lane]), acc);
    }
    float em = (r < nUsers) ? uE[(size_t)r * DIM + lane]
                            : iE[(size_t)(r - nUsers) * DIM + lane];
    float c1 = b2f(cur1B[(size_t)r * DIM + lane]);
    float o = (em + c1 + acc) * (1.0f / 3.0f);
    __builtin_nontemporal_store(o, &out[(size_t)r * DIM + lane]);
}

// ---------------- fallback (round-1 atomic path) ----------------
__global__ __launch_bounds__(256) void spmm_scatter(
    const int* __restrict__ rows, const int* __restrict__ cols,
    const float* __restrict__ vals, const float* __restrict__ srcU,
    const float* __restrict__ srcI, float* __restrict__ dst,
    float scale, int nEdges, int nUsers)
{
    const int lane = threadIdx.x & 63;
    const int wavesPerBlock = blockDim.x >> 6;
    long wave = (long)blockIdx.x * wavesPerBlock + (threadIdx.x >> 6);
    const long nWaves = (long)gridDim.x * wavesPerBlock;
    for (long e = wave; e < nEdges; e += nWaves) {
        const int r = rows[e];
        const int c = cols[e];
        const float v = vals[e] * scale;
        const float* src;
        if (srcI != nullptr) {
            src = (c < nUsers) ? (srcU + (size_t)c * DIM)
                               : (srcI + (size_t)(c - nUsers) * DIM);
        } else {
            src = srcU + (size_t)c * DIM;
        }
        atomicAdd(dst + (size_t)r * DIM + lane, v * src[lane]);
    }
}

__global__ __launch_bounds__(256) void finalize_base(
    const float* __restrict__ userE, const float* __restrict__ itemE,
    const float* __restrict__ cur1, float* __restrict__ out, int nNodes, int nUsers)
{
    const long total4 = (long)nNodes * DIM / 4;
    const long user4  = (long)nUsers * DIM / 4;
    const float inv3 = 1.0f / 3.0f;
    for (long i = (long)blockIdx.x * blockDim.x + threadIdx.x; i < total4;
         i += (long)gridDim.x * blockDim.x) {
        float4 e = (i < user4) ? ((const float4*)userE)[i]
                               : ((const float4*)itemE)[i - user4];
        float4 c = ((const float4*)cur1)[i];
        float4 o;
        o.x = (e.x + c.x) * inv3; o.y = (e.y + c.y) * inv3;
        o.z = (e.z + c.z) * inv3; o.w = (e.w + c.w) * inv3;
        ((float4*)out)[i] = o;
    }
}

// ----------------------------------------------------------------

static inline size_t align256(size_t x) { return (x + 255) & ~(size_t)255; }

extern "C" void kernel_launch(void* const* d_in, const int* in_sizes, int n_in,
                              void* d_out, int out_size, void* d_ws, size_t ws_size,
                              hipStream_t stream)
{
    const int*   rows  = (const int*)d_in[0];
    const int*   cols  = (const int*)d_in[1];
    const float* vals  = (const float*)d_in[2];
    const float* userE = (const float*)d_in[3];
    const float* itemE = (const float*)d_in[4];
    float* out = (float*)d_out;

    const int nE     = in_sizes[0];
    const int nUsers = in_sizes[3] / DIM;
    const int nItems = in_sizes[4] / DIM;
    const int nNodes = nUsers + nItems;
    const int nPart  = (nNodes + PROWS - 1) / PROWS;

    // ws layout:
    //   [region0: max(pairsA, embB+cur1B, cur1_f32-fallback)]
    //     pairsA lives here during preprocessing; after buildCSR it is dead and
    //     k_toBf16/spmm1 overwrite the region with embB (bf16) + cur1B (bf16).
    //   [pairsCSR][rowStart][partStart][partCurPad][partCnt]
    const size_t embBB    = (size_t)nNodes * DIM * sizeof(ushort);   // 38.4 MB
    const size_t cur1BB   = (size_t)nNodes * DIM * sizeof(ushort);   // 38.4 MB
    const size_t cur1F32B = (size_t)nNodes * DIM * sizeof(float);    // fallback
    const size_t pairsAB  = (size_t)nE * sizeof(int2);
    size_t reg0B = embBB + cur1BB;
    if (pairsAB  > reg0B) reg0B = pairsAB;
    if (cur1F32B > reg0B) reg0B = cur1F32B;
    const size_t csrOff   = align256(reg0B);
    const size_t csrB     = (size_t)nE * sizeof(int2);
    const size_t rsOff    = align256(csrOff + csrB);
    const size_t rsB      = ((size_t)nNodes + 1) * sizeof(int);
    const size_t psOff    = align256(rsOff + rsB);
    const size_t psB      = ((size_t)MAXPART + 1) * sizeof(int);
    const size_t pcOff    = align256(psOff + psB);
    const size_t pcB      = (size_t)MAXPART * 16 * sizeof(int);
    const size_t cntOff   = align256(pcOff + pcB);
    const size_t cntB     = (size_t)MAXPART * sizeof(int);
    const size_t required = cntOff + cntB;

    char* ws = (char*)d_ws;
    int2*   pairsA   = (int2*)ws;                    // preprocessing phase
    ushort* embB     = (ushort*)ws;                  // after buildCSR
    ushort* cur1B    = (ushort*)(ws + embBB);
    float*  cur1F32  = (float*)ws;                   // fallback only
    int2*   pairsCSR = (int2*)(ws + csrOff);

    if (ws_size >= required && nNodes <= MAXPART * PROWS && nNodes < (1 << 19)) {
        int* rowStart   = (int*)(ws + rsOff);
        int* partStart  = (int*)(ws + psOff);
        int* partCurPad = (int*)(ws + pcOff);
        int* partCnt    = (int*)(ws + cntOff);

        const int nChunks = (nE + CHUNK - 1) / CHUNK;

        hipMemsetAsync(partCnt, 0, (size_t)nPart * sizeof(int), stream);
        k_phist<<<dim3(512), dim3(256), 0, stream>>>(rows, partCnt, nE, nPart);
        k_pscan<<<dim3(1), dim3(256), 0, stream>>>(partCnt, partStart, partCurPad,
                                                   nPart, nE);
        k_scatterP<<<dim3(nChunks), dim3(256), 0, stream>>>(rows, cols, vals,
                                                            partCurPad, pairsA, nE, nPart);
        k_buildCSR<<<dim3(nPart), dim3(1024), 0, stream>>>(partStart, pairsA, pairsCSR,
                                                           rowStart, nNodes, nE, nPart);
        // pairsA dead; overwrite region with bf16 node matrix
        k_toBf16<<<dim3(2048), dim3(256), 0, stream>>>(userE, itemE, embB,
                                                       nNodes, nUsers);

        const int rowsPerBlock = 4;
        dim3 sgrid((nNodes + rowsPerBlock - 1) / rowsPerBlock), sblk(256);
        k_spmm1<<<sgrid, sblk, 0, stream>>>(rowStart, pairsCSR, embB, cur1B, nNodes);
        k_spmm2<<<sgrid, sblk, 0, stream>>>(rowStart, pairsCSR, cur1B, userE, itemE,
                                            out, nNodes, nUsers);
    } else {
        // fallback: atomic scatter path (round-1)
        hipMemsetAsync(cur1F32, 0, cur1F32B, stream);
        dim3 blk(256);
        spmm_scatter<<<dim3(4096), blk, 0, stream>>>(rows, cols, vals, userE, itemE,
                                                     cur1F32, 1.0f, nE, nUsers);
        finalize_base<<<dim3(2048), blk, 0, stream>>>(userE, itemE, cur1F32, out,
                                                      nNodes, nUsers);
        spmm_scatter<<<dim3(4096), blk, 0, stream>>>(rows, cols, vals, cur1F32, nullptr,
                                                     out, 1.0f / 3.0f, nE, nUsers);
    }
}